// Round 1
// baseline (2275.862 us; speedup 1.0000x reference)
//
#include <hip/hip_runtime.h>
#include <hip/hip_bf16.h>

// Problem constants
#define N_ROWS   16384      // 8*2048
#define EMB_DIM  64
#define NUM_EMB  8192
#define TOP_K    10
#define M_KEEP   16         // pass-1 candidates kept per row (fp32), re-ranked in fp64
#define PERP_W   0.01

// Output layout (all float32, concatenated in return order)
#define QST_OFF   0
#define LOSS_OFF  (N_ROWS * EMB_DIM)                 // 1048576
#define IDX_OFF   (LOSS_OFF + 1)                     // 1048577
#define MIND_OFF  (IDX_OFF + N_ROWS)                 // 1064961
#define PERP_OFF  (MIND_OFF + N_ROWS)                // 1081345

// ws layout (bytes)
#define WS_E2F    0                                  // 8192 floats  (32 KB)
#define WS_COUNTS 32768                              // 8192 ints    (32 KB)
#define WS_LOSS   65536                              // 1 double
#define WS_NVALID 65544                              // 1 int
#define WS_TOPI   65600                              // 16384*16 ints (1 MB)

// ---------------------------------------------------------------------------
// Kernel 0: precompute ||e_k||^2 (fp32, pass-1 ranking only) and zero atomics.
// ---------------------------------------------------------------------------
__global__ __launch_bounds__(256) void vq_init(const float* __restrict__ cb,
                                               float* __restrict__ e2f,
                                               int* __restrict__ counts,
                                               int* __restrict__ nvalid,
                                               double* __restrict__ lossacc) {
    int k = blockIdx.x * 256 + threadIdx.x;   // 0..8191
    counts[k] = 0;
    const float* row = cb + k * EMB_DIM;
    float s = 0.0f;
#pragma unroll 8
    for (int d = 0; d < EMB_DIM; ++d) s += row[d] * row[d];
    e2f[k] = s;
    if (k == 0) { *nvalid = 0; *lossacc = 0.0; }
}

// ---------------------------------------------------------------------------
// Kernel 1: fused distance GEMM + per-row top-16 (fp32 pass 1).
// Block: 256 threads, 64 rows. Streams codebook in 64-code tiles via LDS.
// Thread tile: 4 rows x 4 codes.
// ---------------------------------------------------------------------------
__global__ __launch_bounds__(256) void vq_gemm_topk(const float* __restrict__ inp,
                                                    const float* __restrict__ cb,
                                                    const float* __restrict__ e2f,
                                                    int* __restrict__ topi_g) {
    __shared__ float a_t[64][68];     // [d][row], pad 68 -> 16B-aligned rows, conflict-light
    __shared__ float b_t[64][68];     // [d][code]
    __shared__ float dist_t[64][65];  // [code][row] -> merge reads conflict-free
    __shared__ float x2s[64];
    __shared__ float topv[64][17];
    __shared__ int   topi[64][17];

    const int tid  = threadIdx.x;
    const int row0 = blockIdx.x * 64;

    // init top lists
    for (int i = tid; i < 64 * M_KEEP; i += 256) {
        topv[i >> 4][i & 15] = 3.0e38f;
        topi[i >> 4][i & 15] = 0x7fffffff;
    }

    // stage A (inputs tile) transposed: thread -> (row = tid>>2, d-quarter = (tid&3)*16)
    {
        const int r  = tid >> 2;
        const int dq = (tid & 3) << 4;
        const float4* src = (const float4*)(inp + (size_t)(row0 + r) * EMB_DIM + dq);
        float4 v0 = src[0], v1 = src[1], v2 = src[2], v3 = src[3];
        a_t[dq +  0][r] = v0.x; a_t[dq +  1][r] = v0.y; a_t[dq +  2][r] = v0.z; a_t[dq +  3][r] = v0.w;
        a_t[dq +  4][r] = v1.x; a_t[dq +  5][r] = v1.y; a_t[dq +  6][r] = v1.z; a_t[dq +  7][r] = v1.w;
        a_t[dq +  8][r] = v2.x; a_t[dq +  9][r] = v2.y; a_t[dq + 10][r] = v2.z; a_t[dq + 11][r] = v2.w;
        a_t[dq + 12][r] = v3.x; a_t[dq + 13][r] = v3.y; a_t[dq + 14][r] = v3.z; a_t[dq + 15][r] = v3.w;
    }
    __syncthreads();

    // per-row ||x||^2 (fp32, pass-1 only)
    if (tid < 64) {
        float s = 0.0f;
#pragma unroll 8
        for (int d = 0; d < EMB_DIM; ++d) s += a_t[d][tid] * a_t[d][tid];
        x2s[tid] = s;
    }

    const int tr = tid >> 4;   // 0..15 (row group of 4)
    const int tc = tid & 15;   // 0..15 (code group of 4)

    for (int t = 0; t < NUM_EMB / 64; ++t) {
        __syncthreads();   // protect b_t / dist_t reuse (also publishes x2s on t==0)

        // stage B (codebook tile) transposed
        {
            const int c  = tid >> 2;
            const int dq = (tid & 3) << 4;
            const float4* src = (const float4*)(cb + (size_t)(t * 64 + c) * EMB_DIM + dq);
            float4 v0 = src[0], v1 = src[1], v2 = src[2], v3 = src[3];
            b_t[dq +  0][c] = v0.x; b_t[dq +  1][c] = v0.y; b_t[dq +  2][c] = v0.z; b_t[dq +  3][c] = v0.w;
            b_t[dq +  4][c] = v1.x; b_t[dq +  5][c] = v1.y; b_t[dq +  6][c] = v1.z; b_t[dq +  7][c] = v1.w;
            b_t[dq +  8][c] = v2.x; b_t[dq +  9][c] = v2.y; b_t[dq + 10][c] = v2.z; b_t[dq + 11][c] = v2.w;
            b_t[dq + 12][c] = v3.x; b_t[dq + 13][c] = v3.y; b_t[dq + 14][c] = v3.z; b_t[dq + 15][c] = v3.w;
        }
        __syncthreads();

        // 4x4 dot products over d=0..63
        float acc00=0,acc01=0,acc02=0,acc03=0;
        float acc10=0,acc11=0,acc12=0,acc13=0;
        float acc20=0,acc21=0,acc22=0,acc23=0;
        float acc30=0,acc31=0,acc32=0,acc33=0;
#pragma unroll 8
        for (int d = 0; d < EMB_DIM; ++d) {
            float4 av = *(const float4*)&a_t[d][tr << 2];
            float4 bv = *(const float4*)&b_t[d][tc << 2];
            acc00 += av.x * bv.x; acc01 += av.x * bv.y; acc02 += av.x * bv.z; acc03 += av.x * bv.w;
            acc10 += av.y * bv.x; acc11 += av.y * bv.y; acc12 += av.y * bv.z; acc13 += av.y * bv.w;
            acc20 += av.z * bv.x; acc21 += av.z * bv.y; acc22 += av.z * bv.z; acc23 += av.z * bv.w;
            acc30 += av.w * bv.x; acc31 += av.w * bv.y; acc32 += av.w * bv.z; acc33 += av.w * bv.w;
        }

        // distances: d = x2 + e2 - 2*dot, store [code][row]
        {
            float4 e2v = *(const float4*)(e2f + t * 64 + (tc << 2));
            float x0 = x2s[(tr << 2) + 0], x1 = x2s[(tr << 2) + 1];
            float x2v = x2s[(tr << 2) + 2], x3 = x2s[(tr << 2) + 3];
            int cb0 = tc << 2, rb = tr << 2;
            dist_t[cb0 + 0][rb + 0] = x0 + e2v.x - 2.0f * acc00;
            dist_t[cb0 + 1][rb + 0] = x0 + e2v.y - 2.0f * acc01;
            dist_t[cb0 + 2][rb + 0] = x0 + e2v.z - 2.0f * acc02;
            dist_t[cb0 + 3][rb + 0] = x0 + e2v.w - 2.0f * acc03;
            dist_t[cb0 + 0][rb + 1] = x1 + e2v.x - 2.0f * acc10;
            dist_t[cb0 + 1][rb + 1] = x1 + e2v.y - 2.0f * acc11;
            dist_t[cb0 + 2][rb + 1] = x1 + e2v.z - 2.0f * acc12;
            dist_t[cb0 + 3][rb + 1] = x1 + e2v.w - 2.0f * acc13;
            dist_t[cb0 + 0][rb + 2] = x2v + e2v.x - 2.0f * acc20;
            dist_t[cb0 + 1][rb + 2] = x2v + e2v.y - 2.0f * acc21;
            dist_t[cb0 + 2][rb + 2] = x2v + e2v.z - 2.0f * acc22;
            dist_t[cb0 + 3][rb + 2] = x2v + e2v.w - 2.0f * acc23;
            dist_t[cb0 + 0][rb + 3] = x3 + e2v.x - 2.0f * acc30;
            dist_t[cb0 + 1][rb + 3] = x3 + e2v.y - 2.0f * acc31;
            dist_t[cb0 + 2][rb + 3] = x3 + e2v.z - 2.0f * acc32;
            dist_t[cb0 + 3][rb + 3] = x3 + e2v.w - 2.0f * acc33;
        }
        __syncthreads();

        // merge tile into per-row top-16 (one thread per row; codes in ascending
        // index order -> JAX top_k tie-break (lower index first) preserved by
        // strict-< insert and insert-after-equals)
        if (tid < 64) {
            const int row = tid;
            float worst = topv[row][M_KEEP - 1];
            for (int c2 = 0; c2 < 64; ++c2) {
                float v = dist_t[c2][row];
                if (v < worst) {
                    int p = M_KEEP - 1;
                    while (p > 0 && topv[row][p - 1] > v) {
                        topv[row][p] = topv[row][p - 1];
                        topi[row][p] = topi[row][p - 1];
                        --p;
                    }
                    topv[row][p] = v;
                    topi[row][p] = t * 64 + c2;
                    worst = topv[row][M_KEEP - 1];
                }
            }
        }
    }
    __syncthreads();

    // dump candidate indices
    for (int i = tid; i < 64 * M_KEEP; i += 256) {
        int r = i >> 4, e = i & 15;
        topi_g[(size_t)(row0 + r) * M_KEEP + e] = topi[r][e];
    }
}

// ---------------------------------------------------------------------------
// Kernel 2: fp64 re-rank of 16 candidates, Gumbel-max sample, outputs + atomics.
// One wave per row; 4 rows per 256-thread block.
// ---------------------------------------------------------------------------
__global__ __launch_bounds__(256) void vq_finalize(const float* __restrict__ inp,
                                                   const float* __restrict__ cb,
                                                   const float* __restrict__ gumbel,
                                                   const int* __restrict__ topi_g,
                                                   float* __restrict__ out,
                                                   int* __restrict__ counts,
                                                   int* __restrict__ nvalid,
                                                   double* __restrict__ lossacc) {
    __shared__ double xs[4][64];
    __shared__ double dvs[4][16];
    __shared__ int    dis[4][16];

    const int tid  = threadIdx.x;
    const int w    = tid >> 6;
    const int lane = tid & 63;
    const int row  = blockIdx.x * 4 + w;

    const float xf = inp[(size_t)row * EMB_DIM + lane];
    const double xd = (double)xf;
    xs[w][lane] = xd;

    // wave-wide ||x||^2 in fp64
    double x2 = xd * xd;
#pragma unroll
    for (int off = 32; off >= 1; off >>= 1) x2 += __shfl_xor(x2, off);
    const bool valid = sqrt(x2) > 1e-6;

    __syncthreads();  // publish xs (uniform path; also covers any scheduling quirk)

    if (lane < M_KEEP) {
        const int ci = topi_g[(size_t)row * M_KEEP + lane];
        const float* e = cb + (size_t)ci * EMB_DIM;
        double dot = 0.0, ee = 0.0;
#pragma unroll 8
        for (int d = 0; d < EMB_DIM; ++d) {
            double ed = (double)e[d];
            dot = fma(xs[w][d], ed, dot);
            ee  = fma(ed, ed, ee);
        }
        dvs[w][lane] = x2 + ee - 2.0 * dot;
        dis[w][lane] = ci;
    }
    __syncthreads();

    int   cidx = 0;
    float mind = 0.0f;
    if (lane == 0) {
        // stable insertion sort by (distance, index) — JAX top_k tie-break
        double sv[M_KEEP]; int si[M_KEEP];
        for (int k = 0; k < M_KEEP; ++k) {
            double v = dvs[w][k]; int ii = dis[w][k];
            int p = k;
            while (p > 0 && (sv[p - 1] > v || (sv[p - 1] == v && si[p - 1] > ii))) {
                sv[p] = sv[p - 1]; si[p] = si[p - 1]; --p;
            }
            sv[p] = v; si[p] = ii;
        }
        // Gumbel-max over top-10 (argmax keeps first max, like jnp.argmax)
        const float* g = gumbel + (size_t)row * TOP_K;
        float best = -3.0e38f; int bj = 0;
        for (int k = 0; k < TOP_K; ++k) {
            float sc = (float)(-sv[k]) + g[k];
            if (sc > best) { best = sc; bj = k; }
        }
        cidx = si[bj];
        mind = (float)sv[bj];
    }
    cidx = __shfl(cidx, 0);
    mind = __shfl(mind, 0);

    const float vm = valid ? 1.0f : 0.0f;
    const float q  = cb[(size_t)cidx * EMB_DIM + lane];
    const float qv = q * vm;
    out[QST_OFF + (size_t)row * EMB_DIM + lane] = xf + (qv - xf);

    // loss term uses UNMASKED q_valid, masked by vm
    double dq = (double)q - xd;
    double l  = dq * dq * (double)vm;
#pragma unroll
    for (int off = 32; off >= 1; off >>= 1) l += __shfl_xor(l, off);

    if (lane == 0) {
        atomicAdd(lossacc, l);
        if (valid) {
            atomicAdd(&counts[cidx], 1);
            atomicAdd(nvalid, 1);
        }
        out[IDX_OFF + row]  = valid ? (float)cidx : 0.0f;
        out[MIND_OFF + row] = valid ? mind : 0.0f;
    }
}

// ---------------------------------------------------------------------------
// Kernel 3: perplexity + total loss scalars.
// ---------------------------------------------------------------------------
__global__ __launch_bounds__(256) void vq_scalars(const int* __restrict__ counts,
                                                  const int* __restrict__ nvalid,
                                                  const double* __restrict__ lossacc,
                                                  float* __restrict__ out) {
    __shared__ double red[256];
    const int tid = threadIdx.x;
    int nv_i = *nvalid;
    double nv = (double)(nv_i > 0 ? nv_i : 1);

    double h = 0.0;
    for (int k = tid; k < NUM_EMB; k += 256) {
        double p = (double)counts[k] / nv;
        h += p * log(p + 1e-10);
    }
    red[tid] = h;
    __syncthreads();
    for (int s = 128; s >= 1; s >>= 1) {
        if (tid < s) red[tid] += red[tid + s];
        __syncthreads();
    }
    if (tid == 0) {
        double H = red[0];                       // sum p*log(p+1e-10)
        double perp = exp(-H);
        double ploss = -log(perp + 1e-10);
        double lvq = (*lossacc) / (nv * (double)EMB_DIM);
        out[LOSS_OFF] = (float)(lvq + PERP_W * ploss);
        out[PERP_OFF] = (float)perp;
    }
}

// ---------------------------------------------------------------------------
extern "C" void kernel_launch(void* const* d_in, const int* in_sizes, int n_in,
                              void* d_out, int out_size, void* d_ws, size_t ws_size,
                              hipStream_t stream) {
    const float* inp    = (const float*)d_in[0];  // [16384, 64]
    const float* cb     = (const float*)d_in[1];  // [8192, 64]
    const float* gumbel = (const float*)d_in[2];  // [16384, 10]
    float* out = (float*)d_out;

    char* ws = (char*)d_ws;
    float*  e2f     = (float*)(ws + WS_E2F);
    int*    counts  = (int*)(ws + WS_COUNTS);
    double* lossacc = (double*)(ws + WS_LOSS);
    int*    nvalid  = (int*)(ws + WS_NVALID);
    int*    topi_g  = (int*)(ws + WS_TOPI);

    vq_init<<<NUM_EMB / 256, 256, 0, stream>>>(cb, e2f, counts, nvalid, lossacc);
    vq_gemm_topk<<<N_ROWS / 64, 256, 0, stream>>>(inp, cb, e2f, topi_g);
    vq_finalize<<<N_ROWS / 4, 256, 0, stream>>>(inp, cb, gumbel, topi_g, out,
                                                counts, nvalid, lossacc);
    vq_scalars<<<1, 256, 0, stream>>>(counts, nvalid, lossacc, out);
}